// Round 3
// baseline (1117.445 us; speedup 1.0000x reference)
//
#include <hip/hip_runtime.h>
#include <math.h>

#define NN 50000
#define KK 12
#define DD 64

typedef unsigned short u16;
typedef __attribute__((ext_vector_type(4))) float f32x4;
typedef __attribute__((ext_vector_type(8))) short short8;

__device__ inline u16 f2b(float x){
  union { float f; unsigned u; } v; v.f = x;
  unsigned r = v.u + 0x7fffu + ((v.u >> 16) & 1u);
  return (u16)(r >> 16);
}
__device__ inline float b2f(u16 b){
  union { unsigned u; float f; } v; v.u = ((unsigned)b) << 16; return v.f;
}
__device__ inline float sp_(float x){
  return fmaxf(x, 0.f) + log1pf(expf(-fabsf(x)));
}
__device__ inline f32x4 mfma16(short8 a, short8 b, f32x4 c){
  return __builtin_amdgcn_mfma_f32_16x16x32_bf16(a, b, c, 0, 0, 0);
}
// A/B fragment load from padded [rows][72] bf16 LDS tile.
// row = base + (lane&15), k = ks*32 + (lane>>4)*8 + j  (8 consecutive bf16 = 16B)
__device__ inline short8 ldfrag(const u16* lds, int base, int lane, int ks){
  return *(const short8*)&lds[(base + (lane & 15))*72 + ks*32 + (lane >> 4)*8];
}
// Stage 192x64 fp32 -> bf16 LDS [192][72] (+8 bf16 row pad keeps 16B alignment,
// spreads 16-row fragment reads across banks)
__device__ inline void stage_tile192(const float* src, u16* ldsA, int t){
  #pragma unroll
  for (int i = 0; i < 12; ++i){
    int f4 = t + i*256;
    int m = f4 >> 4, d = (f4 & 15) * 4;
    const float4 v = *(const float4*)(src + m*64 + d);
    ushort4 b; b.x = f2b(v.x); b.y = f2b(v.y); b.z = f2b(v.z); b.w = f2b(v.w);
    *(ushort4*)&ldsA[m*72 + d] = b;
  }
}
// Stage one 64x64 bf16 weight matrix (W^T layout: [out_col][k]) into [64][72]
__device__ inline void stage_w(const u16* wbmat, u16* ldsB, int t){
  #pragma unroll
  for (int i = 0; i < 4; ++i){
    int q = t + i*256;
    int j = q >> 4, d = (q & 15) * 4;
    *(ushort4*)&ldsB[j*72 + d] = *(const ushort4*)(wbmat + j*64 + d);
  }
}

// ---- weight convert: 9 mats [64 out][64 k] bf16, W^T layout ----
// mat = fam*3 + part; fam 0=W_edge,1=W_att1,2=W_val; part 0=self,1=nbr,2=edge
__global__ void kw_conv(const float* We, const float* Wa, const float* Wv, u16* wb){
  int gid = blockIdx.x*256 + threadIdx.x;
  if (gid >= 9*4096) return;
  int mat = gid >> 12, rem = gid & 4095;
  int j = rem >> 6, d = rem & 63;
  int fam = mat / 3, part = mat % 3;
  int c = part*64 + d;
  float v;
  if (fam == 0) v = We[c*64 + j];
  else {
    const float* W = (fam == 1) ? Wa : Wv;
    v = W[(j >> 4)*3072 + c*16 + (j & 15)];   // (H,C,A), j = h*16+a
  }
  wb[mat*4096 + j*64 + d] = f2b(v);
}

// ---- mask fix (lens==0 row) + global masked count ----
__global__ void km_mask(const float* masks, float* maskf, float* stats){
  int t = threadIdx.x;
  int n = blockIdx.x*256 + t;
  float len = 0.f;
  if (n < NN){
    float row[KK];
    #pragma unroll
    for (int k = 0; k < KK; ++k){ row[k] = masks[n*KK + k]; len += row[k]; }
    if (len == 0.f){
      #pragma unroll
      for (int k = 0; k < KK; ++k) row[k] = (k == 0) ? 1.f : 0.f;
      len = 1.f;
    }
    #pragma unroll
    for (int k = 0; k < KK; ++k) maskf[n*KK + k] = row[k];
  }
  __shared__ float red[256];
  red[t] = len; __syncthreads();
  for (int s = 128; s > 0; s >>= 1){ if (t < s) red[t] += red[t + s]; __syncthreads(); }
  if (t == 0) atomicAdd(&stats[0], red[0]);
}

// ---- node projections: 6 x (node @ W_part); self parts fp32, nbr parts bf16 ----
__global__ __launch_bounds__(256,2) void kp_proj(const float* node, const u16* wb,
    float* ps_e, float* ps_a, float* ps_v, u16* pn_e, u16* pn_a, u16* pn_v){
  __shared__ u16 ldsA[64*72];
  __shared__ u16 ldsB[6*64*72];
  int t = threadIdx.x;
  int node0 = blockIdx.x*64;
  #pragma unroll
  for (int i = 0; i < 4; ++i){
    int f4 = t + i*256;
    int m = f4 >> 4, d = (f4 & 15)*4;
    float4 v = make_float4(0.f,0.f,0.f,0.f);
    if (node0 + m < NN) v = *(const float4*)(node + (size_t)(node0 + m)*64 + d);
    ushort4 b; b.x=f2b(v.x); b.y=f2b(v.y); b.z=f2b(v.z); b.w=f2b(v.w);
    *(ushort4*)&ldsA[m*72 + d] = b;
  }
  #pragma unroll
  for (int i = 0; i < 24; ++i){
    int q = t + i*256;                  // 6144 ushort4
    int p = q >> 10, r = q & 1023;
    int j = r >> 4, d = (r & 15)*4;
    int mat = (p % 3)*3 + (p / 3);      // p 0..2 self of e/a/v ; 3..5 nbr
    *(ushort4*)&ldsB[(p*64 + j)*72 + d] = *(const ushort4*)(wb + mat*4096 + j*64 + d);
  }
  __syncthreads();
  int lane = t & 63, w = t >> 6;
  int m0 = w*16;
  short8 a0 = ldfrag(ldsA, m0, lane, 0);
  short8 a1 = ldfrag(ldsA, m0, lane, 1);
  float* psArr[3] = {ps_e, ps_a, ps_v};
  u16*  pnArr[3] = {pn_e, pn_a, pn_v};
  #pragma unroll
  for (int p = 0; p < 6; ++p){
    const u16* B = &ldsB[p*64*72];
    #pragma unroll
    for (int nt = 0; nt < 4; ++nt){
      short8 b0 = ldfrag(B, nt*16, lane, 0);
      short8 b1 = ldfrag(B, nt*16, lane, 1);
      f32x4 acc = {0.f,0.f,0.f,0.f};
      acc = mfma16(a0, b0, acc);
      acc = mfma16(a1, b1, acc);
      int col = nt*16 + (lane & 15);
      #pragma unroll
      for (int r = 0; r < 4; ++r){
        int nrow = node0 + m0 + (lane >> 4)*4 + r;   // C/D: row=(l>>4)*4+r, col=l&15
        if (nrow < NN){
          if (p < 3) psArr[p][(size_t)nrow*64 + col] = acc[r];
          else       pnArr[p-3][(size_t)nrow*64 + col] = f2b(acc[r]);
        }
      }
    }
  }
}

// ---- e_lin masked stats (sum, sumsq per channel) ----
__global__ __launch_bounds__(256,2) void k1_estats(const float* edgef, const int* nidx,
    const float* maskf, const float* ps_e, const u16* pn_e, const float* b_edge,
    const u16* wb, float* stats){
  __shared__ u16 ldsA[192*72];
  __shared__ u16 ldsB[64*72];
  __shared__ float sred[128];
  int t = threadIdx.x;
  int node0 = blockIdx.x*16;
  int e0 = node0*KK;
  stage_tile192(edgef + (size_t)e0*64, ldsA, t);
  stage_w(wb + 2*4096, ldsB, t);
  if (t < 128) sred[t] = 0.f;
  __syncthreads();
  int lane = t & 63, w = t >> 6;
  short8 B[4][2];
  #pragma unroll
  for (int nt = 0; nt < 4; ++nt){ B[nt][0] = ldfrag(ldsB, nt*16, lane, 0); B[nt][1] = ldfrag(ldsB, nt*16, lane, 1); }
  #pragma unroll
  for (int mi = 0; mi < 3; ++mi){
    int mt = w + mi*4;
    short8 a0 = ldfrag(ldsA, mt*16, lane, 0);
    short8 a1 = ldfrag(ldsA, mt*16, lane, 1);
    #pragma unroll
    for (int nt = 0; nt < 4; ++nt){
      f32x4 acc = {0.f,0.f,0.f,0.f};
      acc = mfma16(a0, B[nt][0], acc);
      acc = mfma16(a1, B[nt][1], acc);
      int col = nt*16 + (lane & 15);
      float be = b_edge[col];
      float s = 0.f, q = 0.f;
      #pragma unroll
      for (int r = 0; r < 4; ++r){
        int row = mt*16 + (lane >> 4)*4 + r;
        int n = node0 + row/KK, kk = row % KK;
        int idx = nidx[n*KK + kk];
        float m = maskf[n*KK + kk];
        float v = acc[r] + ps_e[(size_t)n*64 + col] + b2f(pn_e[(size_t)idx*64 + col]) + be;
        s += v*m; q += v*v*m;
      }
      s += __shfl_xor(s, 16); s += __shfl_xor(s, 32);
      q += __shfl_xor(q, 16); q += __shfl_xor(q, 32);
      if (lane < 16){ atomicAdd(&sred[col], s); atomicAdd(&sred[64 + col], q); }
    }
  }
  __syncthreads();
  if (t < 128) atomicAdd(&stats[64 + t], sred[t]);
}

// ---- finalize BN: A = g/sqrt(var+eps), B = b - mean*A ----
__global__ void k_fin(const float* g, const float* b, float* stats, int sumoff, int outoff, float cntfix){
  int j = threadIdx.x;
  float cnt = (cntfix > 0.f) ? cntfix : stats[0];
  float mean = stats[sumoff + j] / cnt;
  float var = stats[sumoff + 64 + j] / cnt - mean*mean;
  var = fmaxf(var, 0.f);
  float A = g[j] / sqrtf(var + 1e-5f);
  stats[outoff + j] = A;
  stats[outoff + 64 + j] = b[j] - mean*A;
}

// ---- main: e_lin -> edge_updated -> h1 -> logits -> softmax -> v -> p stats ----
__global__ __launch_bounds__(256,2) void k3_main(const float* edgef, const int* nidx,
    const float* maskf, const float* ps_e, const u16* pn_e, const float* ps_a, const u16* pn_a,
    const float* ps_v, const u16* pn_v, const float* b_edge, const float* b_att1,
    const float* W_att2, const float* b_att2, const float* b_val,
    const u16* wb, float* stats, float* out_edge, float* att_out){
  __shared__ u16 ldsA[192*72];
  __shared__ u16 ldsBe[64*72];
  __shared__ u16 ldsBa[64*72];
  __shared__ u16 ldsBv[64*72];
  __shared__ float ldsLg[192*4];
  __shared__ float ldsAtt[192*4];
  __shared__ float sred[128];
  int t = threadIdx.x;
  int node0 = blockIdx.x*16;
  int e0 = node0*KK;
  stage_tile192(edgef + (size_t)e0*64, ldsA, t);
  stage_w(wb + 2*4096, ldsBe, t);
  stage_w(wb + 5*4096, ldsBa, t);
  stage_w(wb + 8*4096, ldsBv, t);
  if (t < 128) sred[t] = 0.f;
  __syncthreads();
  int lane = t & 63, w = t >> 6;

  // phase 1: e_lin GEMM, edge_updated (write d_out + overwrite ldsA in place)
  {
    short8 B[4][2];
    #pragma unroll
    for (int nt = 0; nt < 4; ++nt){ B[nt][0] = ldfrag(ldsBe, nt*16, lane, 0); B[nt][1] = ldfrag(ldsBe, nt*16, lane, 1); }
    #pragma unroll
    for (int mi = 0; mi < 3; ++mi){
      int mt = w + mi*4;
      short8 a0 = ldfrag(ldsA, mt*16, lane, 0);
      short8 a1 = ldfrag(ldsA, mt*16, lane, 1);
      #pragma unroll
      for (int nt = 0; nt < 4; ++nt){
        f32x4 acc = {0.f,0.f,0.f,0.f};
        acc = mfma16(a0, B[nt][0], acc);
        acc = mfma16(a1, B[nt][1], acc);
        int col = nt*16 + (lane & 15);
        float Ae = stats[192 + col], Be = stats[256 + col], be = b_edge[col];
        #pragma unroll
        for (int r = 0; r < 4; ++r){
          int row = mt*16 + (lane >> 4)*4 + r;
          int n = node0 + row/KK, kk = row % KK;
          int idx = nidx[n*KK + kk];
          float m = maskf[n*KK + kk];
          float elin = acc[r] + ps_e[(size_t)n*64 + col] + b2f(pn_e[(size_t)idx*64 + col]) + be;
          float ebn = Ae*elin + Be;
          float orig = b2f(ldsA[row*72 + col]);
          float eu = sp_(orig + ebn*m);
          out_edge[((size_t)e0 + row)*64 + col] = eu;
          ldsA[row*72 + col] = f2b(eu);
        }
      }
    }
  }
  __syncthreads();
  // phase 2: h1 GEMM + logits
  {
    short8 B[4][2];
    #pragma unroll
    for (int nt = 0; nt < 4; ++nt){ B[nt][0] = ldfrag(ldsBa, nt*16, lane, 0); B[nt][1] = ldfrag(ldsBa, nt*16, lane, 1); }
    #pragma unroll
    for (int mi = 0; mi < 3; ++mi){
      int mt = w + mi*4;
      short8 a0 = ldfrag(ldsA, mt*16, lane, 0);
      short8 a1 = ldfrag(ldsA, mt*16, lane, 1);
      #pragma unroll
      for (int nt = 0; nt < 4; ++nt){
        f32x4 acc = {0.f,0.f,0.f,0.f};
        acc = mfma16(a0, B[nt][0], acc);
        acc = mfma16(a1, B[nt][1], acc);
        int col = nt*16 + (lane & 15);
        float w2 = W_att2[col], ba1 = b_att1[col];
        #pragma unroll
        for (int r = 0; r < 4; ++r){
          int row = mt*16 + (lane >> 4)*4 + r;
          int n = node0 + row/KK, kk = row % KK;
          int idx = nidx[n*KK + kk];
          float h1 = sp_(acc[r] + ps_a[(size_t)n*64 + col] + b2f(pn_a[(size_t)idx*64 + col]) + ba1);
          float lg = h1 * w2;
          lg += __shfl_xor(lg, 1); lg += __shfl_xor(lg, 2);
          lg += __shfl_xor(lg, 4); lg += __shfl_xor(lg, 8);
          if ((lane & 15) == 0) ldsLg[row*4 + nt] = lg + b_att2[nt];
        }
      }
    }
  }
  __syncthreads();
  // phase 3: masked softmax over K per (node, head)
  if (t < 64){
    int nl = t >> 2, h = t & 3;
    int n = node0 + nl;
    float mrow[KK], lrow[KK];
    #pragma unroll
    for (int k = 0; k < KK; ++k){ mrow[k] = maskf[(size_t)n*KK + k]; lrow[k] = ldsLg[(nl*KK + k)*4 + h]; }
    float mx = -3.0e38f;
    #pragma unroll
    for (int k = 0; k < KK; ++k) if (mrow[k] > 0.f) mx = fmaxf(mx, lrow[k]);
    float ssum = 0.f; float ee[KK];
    #pragma unroll
    for (int k = 0; k < KK; ++k){ float e = (mrow[k] > 0.f) ? expf(lrow[k] - mx) : 0.f; ee[k] = e; ssum += e; }
    float inv = 1.f / ssum;
    #pragma unroll
    for (int k = 0; k < KK; ++k){
      float a = ee[k]*inv;
      ldsAtt[(nl*KK + k)*4 + h] = a;
      att_out[((size_t)n*KK + k)*4 + h] = a;
    }
  }
  __syncthreads();
  // phase 4: v GEMM + p = att*v, masked stats
  {
    short8 B[4][2];
    #pragma unroll
    for (int nt = 0; nt < 4; ++nt){ B[nt][0] = ldfrag(ldsBv, nt*16, lane, 0); B[nt][1] = ldfrag(ldsBv, nt*16, lane, 1); }
    #pragma unroll
    for (int mi = 0; mi < 3; ++mi){
      int mt = w + mi*4;
      short8 a0 = ldfrag(ldsA, mt*16, lane, 0);
      short8 a1 = ldfrag(ldsA, mt*16, lane, 1);
      #pragma unroll
      for (int nt = 0; nt < 4; ++nt){
        f32x4 acc = {0.f,0.f,0.f,0.f};
        acc = mfma16(a0, B[nt][0], acc);
        acc = mfma16(a1, B[nt][1], acc);
        int col = nt*16 + (lane & 15);
        float bv = b_val[col];
        float s = 0.f, q = 0.f;
        #pragma unroll
        for (int r = 0; r < 4; ++r){
          int row = mt*16 + (lane >> 4)*4 + r;
          int n = node0 + row/KK, kk = row % KK;
          int idx = nidx[n*KK + kk];
          float m = maskf[n*KK + kk];
          float v = acc[r] + ps_v[(size_t)n*64 + col] + b2f(pn_v[(size_t)idx*64 + col]) + bv;
          float p = ldsAtt[row*4 + nt] * v;
          s += p*m; q += p*p*m;
        }
        s += __shfl_xor(s, 16); s += __shfl_xor(s, 32);
        q += __shfl_xor(q, 16); q += __shfl_xor(q, 32);
        if (lane < 16){ atomicAdd(&sred[col], s); atomicAdd(&sred[64 + col], q); }
      }
    }
  }
  __syncthreads();
  if (t < 128) atomicAdd(&stats[320 + t], sred[t]);
}

// ---- pool: recompute v, p_bn -> softplus -> masked pool -> out stats ----
// pooled is written into the node slot of d_out (overwritten in-place by k7_out).
__global__ __launch_bounds__(256,2) void k5_pool(const float* eu, const int* nidx,
    const float* maskf, const float* ps_v, const u16* pn_v, const float* b_val,
    const u16* wb, const float* att_in, float* stats, float* pooled){
  __shared__ u16 ldsA[192*72];
  __shared__ u16 ldsB[64*72];
  __shared__ float ldsAtt[192*4];
  __shared__ float pool[16*64];
  __shared__ float sred[128];
  int t = threadIdx.x;
  int node0 = blockIdx.x*16;
  int e0 = node0*KK;
  stage_tile192(eu + (size_t)e0*64, ldsA, t);
  stage_w(wb + 8*4096, ldsB, t);
  #pragma unroll
  for (int i = 0; i < 3; ++i){ int q = t + i*256; ldsAtt[q] = att_in[(size_t)e0*4 + q]; }
  #pragma unroll
  for (int i = 0; i < 4; ++i) pool[t + i*256] = 0.f;
  if (t < 128) sred[t] = 0.f;
  __syncthreads();
  int lane = t & 63, w = t >> 6;
  short8 B[4][2];
  #pragma unroll
  for (int nt = 0; nt < 4; ++nt){ B[nt][0] = ldfrag(ldsB, nt*16, lane, 0); B[nt][1] = ldfrag(ldsB, nt*16, lane, 1); }
  #pragma unroll
  for (int mi = 0; mi < 3; ++mi){
    int mt = w + mi*4;
    short8 a0 = ldfrag(ldsA, mt*16, lane, 0);
    short8 a1 = ldfrag(ldsA, mt*16, lane, 1);
    #pragma unroll
    for (int nt = 0; nt < 4; ++nt){
      f32x4 acc = {0.f,0.f,0.f,0.f};
      acc = mfma16(a0, B[nt][0], acc);
      acc = mfma16(a1, B[nt][1], acc);
      int col = nt*16 + (lane & 15);
      float bv = b_val[col];
      float Ap = stats[448 + col], Bp = stats[512 + col];
      #pragma unroll
      for (int r = 0; r < 4; ++r){
        int row = mt*16 + (lane >> 4)*4 + r;
        int n = node0 + row/KK, kk = row % KK;
        int idx = nidx[n*KK + kk];
        float m = maskf[n*KK + kk];
        float v = acc[r] + ps_v[(size_t)n*64 + col] + b2f(pn_v[(size_t)idx*64 + col]) + bv;
        float p = ldsAtt[row*4 + nt] * v;
        float head = sp_(Ap*p + Bp) * m;
        atomicAdd(&pool[(row/KK)*64 + col], head);
      }
    }
  }
  __syncthreads();
  int ch = t & 63;
  float s = 0.f, q = 0.f;
  #pragma unroll
  for (int i = 0; i < 4; ++i){
    int qi = t + i*256;
    int nl = qi >> 6;
    float val = pool[qi];
    pooled[((size_t)(node0 + nl))*64 + ch] = val;
    s += val; q += val*val;
  }
  atomicAdd(&sred[ch], s); atomicAdd(&sred[64 + ch], q);
  __syncthreads();
  if (t < 128) atomicAdd(&stats[576 + t], sred[t]);
}

// ---- residual + out BN (in-place: out currently holds pooled) ----
__global__ void k7_out(const float* node, const float* stats, float* out){
  int i = blockIdx.x*256 + threadIdx.x;
  if (i < NN*64){
    int ch = i & 63;
    float pooled = out[i];
    out[i] = node[i] + stats[704 + ch]*pooled + stats[768 + ch];
  }
}

extern "C" void kernel_launch(void* const* d_in, const int* in_sizes, int n_in,
                              void* d_out, int out_size, void* d_ws, size_t ws_size,
                              hipStream_t stream){
  const float* node   = (const float*)d_in[0];
  const float* edgef  = (const float*)d_in[1];
  const int*   nidx   = (const int*)d_in[2];
  const float* masks  = (const float*)d_in[3];
  const float* We     = (const float*)d_in[4];
  const float* b_edge = (const float*)d_in[5];
  const float* g_ebn  = (const float*)d_in[6];
  const float* b_ebn  = (const float*)d_in[7];
  const float* Wa1    = (const float*)d_in[8];
  const float* b_att1 = (const float*)d_in[9];
  const float* Wa2    = (const float*)d_in[10];
  const float* b_att2 = (const float*)d_in[11];
  const float* Wv     = (const float*)d_in[12];
  const float* b_val  = (const float*)d_in[13];
  const float* g_abn  = (const float*)d_in[14];
  const float* b_abn  = (const float*)d_in[15];
  const float* g_obn  = (const float*)d_in[16];
  const float* b_obn  = (const float*)d_in[17];

  float* ps_e   = (float*)d_ws;
  float* ps_a   = ps_e   + (size_t)NN*64;
  float* ps_v   = ps_a   + (size_t)NN*64;
  float* maskf  = ps_v   + (size_t)NN*64;
  float* att    = maskf  + (size_t)NN*KK;
  float* stats  = att    + (size_t)NN*KK*4;
  u16*   pn_e   = (u16*)(stats + 1024);
  u16*   pn_a   = pn_e   + (size_t)NN*64;
  u16*   pn_v   = pn_a   + (size_t)NN*64;
  u16*   wb     = pn_v   + (size_t)NN*64;

  float* out_node = (float*)d_out;          // holds pooled between k5 and k7
  float* out_edge = out_node + (size_t)NN*64;

  hipMemsetAsync(stats, 0, 1024*sizeof(float), stream);
  kw_conv<<<144, 256, 0, stream>>>(We, Wa1, Wv, wb);
  km_mask<<<(NN + 255)/256, 256, 0, stream>>>(masks, maskf, stats);
  kp_proj<<<(NN + 63)/64, 256, 0, stream>>>(node, wb, ps_e, ps_a, ps_v, pn_e, pn_a, pn_v);
  k1_estats<<<NN/16, 256, 0, stream>>>(edgef, nidx, maskf, ps_e, pn_e, b_edge, wb, stats);
  k_fin<<<1, 64, 0, stream>>>(g_ebn, b_ebn, stats, 64, 192, 0.f);
  k3_main<<<NN/16, 256, 0, stream>>>(edgef, nidx, maskf, ps_e, pn_e, ps_a, pn_a, ps_v, pn_v,
      b_edge, b_att1, Wa2, b_att2, b_val, wb, stats, out_edge, att);
  k_fin<<<1, 64, 0, stream>>>(g_abn, b_abn, stats, 320, 448, 0.f);
  k5_pool<<<NN/16, 256, 0, stream>>>(out_edge, nidx, maskf, ps_v, pn_v, b_val, wb, att, stats, out_node);
  k_fin<<<1, 64, 0, stream>>>(g_obn, b_obn, stats, 576, 704, (float)NN);
  k7_out<<<(NN*64 + 255)/256, 256, 0, stream>>>(node, stats, out_node);
}

// Round 4
// 826.897 us; speedup vs baseline: 1.3514x; 1.3514x over previous
//
#include <hip/hip_runtime.h>
#include <math.h>

#define NN 50000
#define KK 12

typedef unsigned short u16;
typedef __attribute__((ext_vector_type(4))) float f32x4;
typedef __attribute__((ext_vector_type(8))) short short8;

__device__ inline u16 f2b(float x){
  union { float f; unsigned u; } v; v.f = x;
  unsigned r = v.u + 0x7fffu + ((v.u >> 16) & 1u);
  return (u16)(r >> 16);
}
__device__ inline float b2f(u16 b){
  union { unsigned u; float f; } v; v.u = ((unsigned)b) << 16; return v.f;
}
// fast softplus: v_exp_f32 + v_log_f32 (error ~1e-6 abs, budget is 0.1875)
__device__ inline float sp_(float x){
  return fmaxf(x, 0.f) + __logf(1.f + __expf(-fabsf(x)));
}
__device__ inline f32x4 mfma16(short8 a, short8 b, f32x4 c){
  return __builtin_amdgcn_mfma_f32_16x16x32_bf16(a, b, c, 0, 0, 0);
}
// A-fragment from padded [rows][72] bf16 LDS tile
__device__ inline short8 ldfrag(const u16* lds, int base, int lane, int ks){
  return *(const short8*)&lds[(base + (lane & 15))*72 + ks*32 + (lane >> 4)*8];
}
// B-fragment straight from global W^T [64][64] bf16 (L1/L2-hot: all blocks share)
__device__ inline short8 ldwfrag(const u16* wmat, int lane, int nt, int ks){
  return *(const short8*)&wmat[(nt*16 + (lane & 15))*64 + ks*32 + (lane >> 4)*8];
}
// Stage 192x64 fp32 -> bf16 LDS [192][72]
__device__ inline void stage_tile192(const float* src, u16* ldsA, int t){
  #pragma unroll
  for (int i = 0; i < 12; ++i){
    int f4 = t + i*256;
    int m = f4 >> 4, d = (f4 & 15) * 4;
    const float4 v = *(const float4*)(src + m*64 + d);
    ushort4 b; b.x = f2b(v.x); b.y = f2b(v.y); b.z = f2b(v.z); b.w = f2b(v.w);
    *(ushort4*)&ldsA[m*72 + d] = b;
  }
}

// ---- weight convert: 9 mats [64 out][64 k] bf16, W^T layout ----
__global__ void kw_conv(const float* We, const float* Wa, const float* Wv, u16* wb){
  int gid = blockIdx.x*256 + threadIdx.x;
  if (gid >= 9*4096) return;
  int mat = gid >> 12, rem = gid & 4095;
  int j = rem >> 6, d = rem & 63;
  int fam = mat / 3, part = mat % 3;
  int c = part*64 + d;
  float v;
  if (fam == 0) v = We[c*64 + j];
  else {
    const float* W = (fam == 1) ? Wa : Wv;
    v = W[(j >> 4)*3072 + c*16 + (j & 15)];   // (H,C,A), j = h*16+a
  }
  wb[mat*4096 + j*64 + d] = f2b(v);
}

// ---- mask fix (lens==0 row) + global masked count ----
__global__ void km_mask(const float* masks, float* maskf, float* stats){
  int t = threadIdx.x;
  int n = blockIdx.x*256 + t;
  float len = 0.f;
  if (n < NN){
    float row[KK];
    #pragma unroll
    for (int k = 0; k < KK; ++k){ row[k] = masks[n*KK + k]; len += row[k]; }
    if (len == 0.f){
      #pragma unroll
      for (int k = 0; k < KK; ++k) row[k] = (k == 0) ? 1.f : 0.f;
      len = 1.f;
    }
    #pragma unroll
    for (int k = 0; k < KK; ++k) maskf[n*KK + k] = row[k];
  }
  __shared__ float red[256];
  red[t] = len; __syncthreads();
  for (int s = 128; s > 0; s >>= 1){ if (t < s) red[t] += red[t + s]; __syncthreads(); }
  if (t == 0) atomicAdd(&stats[0], red[0]);
}

// ---- node projections: 6 x (node @ W_part); self fp32, nbr bf16 ----
__global__ __launch_bounds__(256,4) void kp_proj(const float* node, const u16* wb,
    float* ps_e, float* ps_a, float* ps_v, u16* pn_e, u16* pn_a, u16* pn_v){
  __shared__ u16 ldsA[64*72];
  int t = threadIdx.x;
  int node0 = blockIdx.x*64;
  #pragma unroll
  for (int i = 0; i < 4; ++i){
    int f4 = t + i*256;
    int m = f4 >> 4, d = (f4 & 15)*4;
    float4 v = make_float4(0.f,0.f,0.f,0.f);
    if (node0 + m < NN) v = *(const float4*)(node + (size_t)(node0 + m)*64 + d);
    ushort4 b; b.x=f2b(v.x); b.y=f2b(v.y); b.z=f2b(v.z); b.w=f2b(v.w);
    *(ushort4*)&ldsA[m*72 + d] = b;
  }
  __syncthreads();
  int lane = t & 63, w = t >> 6;
  int m0 = w*16;
  short8 a0 = ldfrag(ldsA, m0, lane, 0);
  short8 a1 = ldfrag(ldsA, m0, lane, 1);
  float* psArr[3] = {ps_e, ps_a, ps_v};
  u16*  pnArr[3] = {pn_e, pn_a, pn_v};
  #pragma unroll
  for (int p = 0; p < 6; ++p){
    const u16* W = wb + ((p % 3)*3 + (p / 3))*4096;
    #pragma unroll
    for (int nt = 0; nt < 4; ++nt){
      short8 b0 = ldwfrag(W, lane, nt, 0);
      short8 b1 = ldwfrag(W, lane, nt, 1);
      f32x4 acc = {0.f,0.f,0.f,0.f};
      acc = mfma16(a0, b0, acc);
      acc = mfma16(a1, b1, acc);
      int col = nt*16 + (lane & 15);
      #pragma unroll
      for (int r = 0; r < 4; ++r){
        int nrow = node0 + m0 + (lane >> 4)*4 + r;
        if (nrow < NN){
          if (p < 3) psArr[p][(size_t)nrow*64 + col] = acc[r];
          else       pnArr[p-3][(size_t)nrow*64 + col] = f2b(acc[r]);
        }
      }
    }
  }
}

// ---- e_lin masked stats ----
__global__ __launch_bounds__(256,4) void k1_estats(const float* edgef, const int* nidx,
    const float* maskf, const float* ps_e, const u16* pn_e, const float* b_edge,
    const u16* wb, float* stats){
  __shared__ u16 ldsA[192*72];
  __shared__ int rPs[192]; __shared__ int rPn[192]; __shared__ float rM[192];
  __shared__ float sred[128];
  int t = threadIdx.x;
  int node0 = blockIdx.x*16;
  int e0 = node0*KK;
  stage_tile192(edgef + (size_t)e0*64, ldsA, t);
  if (t < 192){ rPs[t] = (node0 + t/KK)*64; rPn[t] = nidx[e0 + t]*64; rM[t] = maskf[e0 + t]; }
  if (t < 128) sred[t] = 0.f;
  __syncthreads();
  int lane = t & 63, w = t >> 6;
  const u16* We_ = wb + 2*4096;
  float be4[4];
  #pragma unroll
  for (int nt = 0; nt < 4; ++nt) be4[nt] = b_edge[nt*16 + (lane & 15)];
  #pragma unroll
  for (int mi = 0; mi < 3; ++mi){
    int mt = w + mi*4;
    short8 a0 = ldfrag(ldsA, mt*16, lane, 0);
    short8 a1 = ldfrag(ldsA, mt*16, lane, 1);
    #pragma unroll
    for (int nt = 0; nt < 4; ++nt){
      short8 b0 = ldwfrag(We_, lane, nt, 0);
      short8 b1 = ldwfrag(We_, lane, nt, 1);
      f32x4 acc = {0.f,0.f,0.f,0.f};
      acc = mfma16(a0, b0, acc);
      acc = mfma16(a1, b1, acc);
      int col = nt*16 + (lane & 15);
      float s = 0.f, q = 0.f;
      #pragma unroll
      for (int r = 0; r < 4; ++r){
        int row = mt*16 + (lane >> 4)*4 + r;
        float v = acc[r] + ps_e[rPs[row] + col] + b2f(pn_e[rPn[row] + col]) + be4[nt];
        float m = rM[row];
        s += v*m; q += v*v*m;
      }
      s += __shfl_xor(s, 16); s += __shfl_xor(s, 32);
      q += __shfl_xor(q, 16); q += __shfl_xor(q, 32);
      if (lane < 16){ atomicAdd(&sred[col], s); atomicAdd(&sred[64 + col], q); }
    }
  }
  __syncthreads();
  if (t < 128) atomicAdd(&stats[64 + t], sred[t]);
}

// ---- finalize BN: A = g/sqrt(var+eps), B = b - mean*A ----
__global__ void k_fin(const float* g, const float* b, float* stats, int sumoff, int outoff, float cntfix){
  int j = threadIdx.x;
  float cnt = (cntfix > 0.f) ? cntfix : stats[0];
  float mean = stats[sumoff + j] / cnt;
  float var = stats[sumoff + 64 + j] / cnt - mean*mean;
  var = fmaxf(var, 0.f);
  float A = g[j] / sqrtf(var + 1e-5f);
  stats[outoff + j] = A;
  stats[outoff + 64 + j] = b[j] - mean*A;
}

// ---- main fused kernel ----
__global__ __launch_bounds__(256,4) void k3_main(const float* edgef, const int* nidx,
    const float* maskf, const float* ps_e, const u16* pn_e, const float* ps_a, const u16* pn_a,
    const float* ps_v, const u16* pn_v, const float* b_edge, const float* b_att1,
    const float* W_att2, const float* b_att2, const float* b_val,
    const u16* wb, float* stats, float* out_edge, float* att_out, u16* p_out){
  __shared__ u16 ldsA[192*72];
  __shared__ float ldsLA[192*4];        // logits, then att (reused)
  __shared__ int rPs[192]; __shared__ int rPn[192]; __shared__ float rM[192];
  __shared__ float sred[128];
  int t = threadIdx.x;
  int node0 = blockIdx.x*16;
  int e0 = node0*KK;
  stage_tile192(edgef + (size_t)e0*64, ldsA, t);
  if (t < 192){ rPs[t] = (node0 + t/KK)*64; rPn[t] = nidx[e0 + t]*64; rM[t] = maskf[e0 + t]; }
  if (t < 128) sred[t] = 0.f;
  __syncthreads();
  int lane = t & 63, w = t >> 6;
  int cl = lane & 15;

  // phase 1: e_lin -> edge_updated (write d_out fp32 + overwrite ldsA bf16)
  {
    const u16* W = wb + 2*4096;
    float Ae4[4], Be4[4], be4[4];
    #pragma unroll
    for (int nt = 0; nt < 4; ++nt){
      int col = nt*16 + cl;
      Ae4[nt] = stats[192 + col]; Be4[nt] = stats[256 + col]; be4[nt] = b_edge[col];
    }
    #pragma unroll
    for (int mi = 0; mi < 3; ++mi){
      int mt = w + mi*4;
      short8 a0 = ldfrag(ldsA, mt*16, lane, 0);
      short8 a1 = ldfrag(ldsA, mt*16, lane, 1);
      #pragma unroll
      for (int nt = 0; nt < 4; ++nt){
        short8 b0 = ldwfrag(W, lane, nt, 0);
        short8 b1 = ldwfrag(W, lane, nt, 1);
        f32x4 acc = {0.f,0.f,0.f,0.f};
        acc = mfma16(a0, b0, acc);
        acc = mfma16(a1, b1, acc);
        int col = nt*16 + cl;
        #pragma unroll
        for (int r = 0; r < 4; ++r){
          int row = mt*16 + (lane >> 4)*4 + r;
          float elin = acc[r] + ps_e[rPs[row] + col] + b2f(pn_e[rPn[row] + col]) + be4[nt];
          float ebn = Ae4[nt]*elin + Be4[nt];
          float orig = b2f(ldsA[row*72 + col]);
          float eu = sp_(orig + ebn*rM[row]);
          out_edge[((size_t)e0 + row)*64 + col] = eu;
          ldsA[row*72 + col] = f2b(eu);
        }
      }
    }
  }
  __syncthreads();
  // phase 2: h1 + logits
  {
    const u16* W = wb + 5*4096;
    float w24[4], ba4[4];
    #pragma unroll
    for (int nt = 0; nt < 4; ++nt){
      int col = nt*16 + cl;
      w24[nt] = W_att2[col]; ba4[nt] = b_att1[col];
    }
    #pragma unroll
    for (int mi = 0; mi < 3; ++mi){
      int mt = w + mi*4;
      short8 a0 = ldfrag(ldsA, mt*16, lane, 0);
      short8 a1 = ldfrag(ldsA, mt*16, lane, 1);
      #pragma unroll
      for (int nt = 0; nt < 4; ++nt){
        short8 b0 = ldwfrag(W, lane, nt, 0);
        short8 b1 = ldwfrag(W, lane, nt, 1);
        f32x4 acc = {0.f,0.f,0.f,0.f};
        acc = mfma16(a0, b0, acc);
        acc = mfma16(a1, b1, acc);
        int col = nt*16 + cl;
        #pragma unroll
        for (int r = 0; r < 4; ++r){
          int row = mt*16 + (lane >> 4)*4 + r;
          float h1 = sp_(acc[r] + ps_a[rPs[row] + col] + b2f(pn_a[rPn[row] + col]) + ba4[nt]);
          float lg = h1 * w24[nt];
          lg += __shfl_xor(lg, 1); lg += __shfl_xor(lg, 2);
          lg += __shfl_xor(lg, 4); lg += __shfl_xor(lg, 8);
          if (cl == 0) ldsLA[row*4 + nt] = lg + b_att2[nt];
        }
      }
    }
  }
  __syncthreads();
  // phase 3: masked softmax over K per (node, head); overwrite ldsLA with att
  if (t < 64){
    int nl = t >> 2, h = t & 3;
    float lrow[KK], mrow[KK];
    #pragma unroll
    for (int k = 0; k < KK; ++k){ lrow[k] = ldsLA[(nl*KK + k)*4 + h]; mrow[k] = rM[nl*KK + k]; }
    float mx = -3.0e38f;
    #pragma unroll
    for (int k = 0; k < KK; ++k) if (mrow[k] > 0.f) mx = fmaxf(mx, lrow[k]);
    float ssum = 0.f; float ee[KK];
    #pragma unroll
    for (int k = 0; k < KK; ++k){ float e = (mrow[k] > 0.f) ? __expf(lrow[k] - mx) : 0.f; ee[k] = e; ssum += e; }
    float inv = 1.f / ssum;
    #pragma unroll
    for (int k = 0; k < KK; ++k){
      float a = ee[k]*inv;
      ldsLA[(nl*KK + k)*4 + h] = a;
      att_out[((size_t)(node0 + nl)*KK + k)*4 + h] = a;
    }
  }
  __syncthreads();
  // phase 4: v GEMM + p = att*v, masked stats (+ optional p store for stream-k5)
  {
    const u16* W = wb + 8*4096;
    float bv4[4];
    #pragma unroll
    for (int nt = 0; nt < 4; ++nt) bv4[nt] = b_val[nt*16 + cl];
    #pragma unroll
    for (int mi = 0; mi < 3; ++mi){
      int mt = w + mi*4;
      short8 a0 = ldfrag(ldsA, mt*16, lane, 0);
      short8 a1 = ldfrag(ldsA, mt*16, lane, 1);
      #pragma unroll
      for (int nt = 0; nt < 4; ++nt){
        short8 b0 = ldwfrag(W, lane, nt, 0);
        short8 b1 = ldwfrag(W, lane, nt, 1);
        f32x4 acc = {0.f,0.f,0.f,0.f};
        acc = mfma16(a0, b0, acc);
        acc = mfma16(a1, b1, acc);
        int col = nt*16 + cl;
        float s = 0.f, q = 0.f;
        #pragma unroll
        for (int r = 0; r < 4; ++r){
          int row = mt*16 + (lane >> 4)*4 + r;
          float v = acc[r] + ps_v[rPs[row] + col] + b2f(pn_v[rPn[row] + col]) + bv4[nt];
          float p = ldsLA[row*4 + nt] * v;
          float m = rM[row];
          s += p*m; q += p*p*m;
          if (p_out) p_out[((size_t)e0 + row)*64 + col] = f2b(p);
        }
        s += __shfl_xor(s, 16); s += __shfl_xor(s, 32);
        q += __shfl_xor(q, 16); q += __shfl_xor(q, 32);
        if (lane < 16){ atomicAdd(&sred[col], s); atomicAdd(&sred[64 + col], q); }
      }
    }
  }
  __syncthreads();
  if (t < 128) atomicAdd(&stats[320 + t], sred[t]);
}

// ---- k5 stream path: pool from stored p (bf16), no GEMM/gathers ----
__global__ void k5_stream(const u16* pbuf, const float* maskf, float* stats, float* pooled){
  __shared__ float sred[128];
  int t = threadIdx.x;
  int node0 = blockIdx.x*16;
  int col = t & 63;
  if (t < 128) sred[t] = 0.f;
  __syncthreads();
  float Ap = stats[448 + col], Bp = stats[512 + col];
  float s = 0.f, q = 0.f;
  #pragma unroll
  for (int i = 0; i < 4; ++i){
    int n = node0 + (t >> 6) + i*4;
    float acc = 0.f;
    #pragma unroll
    for (int k = 0; k < KK; ++k){
      float m = maskf[n*KK + k];
      float p = b2f(pbuf[((size_t)(n*KK + k))*64 + col]);
      acc += sp_(Ap*p + Bp) * m;
    }
    pooled[(size_t)n*64 + col] = acc;
    s += acc; q += acc*acc;
  }
  atomicAdd(&sred[col], s); atomicAdd(&sred[64 + col], q);
  __syncthreads();
  if (t < 128) atomicAdd(&stats[576 + t], sred[t]);
}

// ---- k5 fallback: recompute v from edge_updated ----
__global__ __launch_bounds__(256,4) void k5_rec(const float* eu, const int* nidx,
    const float* maskf, const float* ps_v, const u16* pn_v, const float* b_val,
    const u16* wb, const float* att_in, float* stats, float* pooled){
  __shared__ u16 ldsA[192*72];
  __shared__ float ldsAtt[192*4];
  __shared__ float pool[16*64];
  __shared__ int rPs[192]; __shared__ int rPn[192]; __shared__ float rM[192];
  __shared__ float sred[128];
  int t = threadIdx.x;
  int node0 = blockIdx.x*16;
  int e0 = node0*KK;
  stage_tile192(eu + (size_t)e0*64, ldsA, t);
  if (t < 192){ rPs[t] = (node0 + t/KK)*64; rPn[t] = nidx[e0 + t]*64; rM[t] = maskf[e0 + t]; }
  #pragma unroll
  for (int i = 0; i < 3; ++i){ int q = t + i*256; ldsAtt[q] = att_in[(size_t)e0*4 + q]; }
  #pragma unroll
  for (int i = 0; i < 4; ++i) pool[t + i*256] = 0.f;
  if (t < 128) sred[t] = 0.f;
  __syncthreads();
  int lane = t & 63, w = t >> 6;
  int cl = lane & 15;
  const u16* W = wb + 8*4096;
  float bv4[4], Ap4[4], Bp4[4];
  #pragma unroll
  for (int nt = 0; nt < 4; ++nt){
    int col = nt*16 + cl;
    bv4[nt] = b_val[col]; Ap4[nt] = stats[448 + col]; Bp4[nt] = stats[512 + col];
  }
  #pragma unroll
  for (int mi = 0; mi < 3; ++mi){
    int mt = w + mi*4;
    short8 a0 = ldfrag(ldsA, mt*16, lane, 0);
    short8 a1 = ldfrag(ldsA, mt*16, lane, 1);
    #pragma unroll
    for (int nt = 0; nt < 4; ++nt){
      short8 b0 = ldwfrag(W, lane, nt, 0);
      short8 b1 = ldwfrag(W, lane, nt, 1);
      f32x4 acc = {0.f,0.f,0.f,0.f};
      acc = mfma16(a0, b0, acc);
      acc = mfma16(a1, b1, acc);
      int col = nt*16 + cl;
      #pragma unroll
      for (int r = 0; r < 4; ++r){
        int row = mt*16 + (lane >> 4)*4 + r;
        float v = acc[r] + ps_v[rPs[row] + col] + b2f(pn_v[rPn[row] + col]) + bv4[nt];
        float p = ldsAtt[row*4 + nt] * v;
        float head = sp_(Ap4[nt]*p + Bp4[nt]) * rM[row];
        atomicAdd(&pool[(row/KK)*64 + col], head);
      }
    }
  }
  __syncthreads();
  int ch = t & 63;
  float s = 0.f, q = 0.f;
  #pragma unroll
  for (int i = 0; i < 4; ++i){
    int qi = t + i*256;
    float val = pool[qi];
    pooled[((size_t)(node0 + (qi >> 6)))*64 + ch] = val;
    s += val; q += val*val;
  }
  atomicAdd(&sred[ch], s); atomicAdd(&sred[64 + ch], q);
  __syncthreads();
  if (t < 128) atomicAdd(&stats[576 + t], sred[t]);
}

// ---- residual + out BN (in-place: out currently holds pooled) ----
__global__ void k7_out(const float* node, const float* stats, float* out){
  int i = blockIdx.x*256 + threadIdx.x;
  if (i < NN*64){
    int ch = i & 63;
    float pooled = out[i];
    out[i] = node[i] + stats[704 + ch]*pooled + stats[768 + ch];
  }
}

extern "C" void kernel_launch(void* const* d_in, const int* in_sizes, int n_in,
                              void* d_out, int out_size, void* d_ws, size_t ws_size,
                              hipStream_t stream){
  const float* node   = (const float*)d_in[0];
  const float* edgef  = (const float*)d_in[1];
  const int*   nidx   = (const int*)d_in[2];
  const float* masks  = (const float*)d_in[3];
  const float* We     = (const float*)d_in[4];
  const float* b_edge = (const float*)d_in[5];
  const float* g_ebn  = (const float*)d_in[6];
  const float* b_ebn  = (const float*)d_in[7];
  const float* Wa1    = (const float*)d_in[8];
  const float* b_att1 = (const float*)d_in[9];
  const float* Wa2    = (const float*)d_in[10];
  const float* b_att2 = (const float*)d_in[11];
  const float* Wv     = (const float*)d_in[12];
  const float* b_val  = (const float*)d_in[13];
  const float* g_abn  = (const float*)d_in[14];
  const float* b_abn  = (const float*)d_in[15];
  const float* g_obn  = (const float*)d_in[16];
  const float* b_obn  = (const float*)d_in[17];

  float* ps_e   = (float*)d_ws;
  float* ps_a   = ps_e   + (size_t)NN*64;
  float* ps_v   = ps_a   + (size_t)NN*64;
  float* maskf  = ps_v   + (size_t)NN*64;
  float* att    = maskf  + (size_t)NN*KK;
  float* stats  = att    + (size_t)NN*KK*4;
  u16*   pn_e   = (u16*)(stats + 1024);
  u16*   pn_a   = pn_e   + (size_t)NN*64;
  u16*   pn_v   = pn_a   + (size_t)NN*64;
  u16*   wb     = pn_v   + (size_t)NN*64;
  u16*   pbuf   = wb     + 9*4096;
  size_t need   = (size_t)((char*)(pbuf + (size_t)NN*KK*64) - (char*)d_ws);
  bool   use_p  = (ws_size >= need);   // constant per session -> graph-safe

  float* out_node = (float*)d_out;          // holds pooled between k5 and k7
  float* out_edge = out_node + (size_t)NN*64;

  hipMemsetAsync(stats, 0, 1024*sizeof(float), stream);
  kw_conv<<<144, 256, 0, stream>>>(We, Wa1, Wv, wb);
  km_mask<<<(NN + 255)/256, 256, 0, stream>>>(masks, maskf, stats);
  kp_proj<<<(NN + 63)/64, 256, 0, stream>>>(node, wb, ps_e, ps_a, ps_v, pn_e, pn_a, pn_v);
  k1_estats<<<NN/16, 256, 0, stream>>>(edgef, nidx, maskf, ps_e, pn_e, b_edge, wb, stats);
  k_fin<<<1, 64, 0, stream>>>(g_ebn, b_ebn, stats, 64, 192, 0.f);
  k3_main<<<NN/16, 256, 0, stream>>>(edgef, nidx, maskf, ps_e, pn_e, ps_a, pn_a, ps_v, pn_v,
      b_edge, b_att1, Wa2, b_att2, b_val, wb, stats, out_edge, att, use_p ? pbuf : (u16*)nullptr);
  k_fin<<<1, 64, 0, stream>>>(g_abn, b_abn, stats, 320, 448, 0.f);
  if (use_p)
    k5_stream<<<NN/16, 256, 0, stream>>>(pbuf, maskf, stats, out_node);
  else
    k5_rec<<<NN/16, 256, 0, stream>>>(out_edge, nidx, maskf, ps_v, pn_v, b_val, wb, att, stats, out_node);
  k_fin<<<1, 64, 0, stream>>>(g_obn, b_obn, stats, 576, 704, (float)NN);
  k7_out<<<(NN*64 + 255)/256, 256, 0, stream>>>(node, stats, out_node);
}